// Round 2
// baseline (106.799 us; speedup 1.0000x reference)
//
#include <hip/hip_runtime.h>
#include <math.h>

#define NQ 4
#define DIM 16
#define K 512

typedef float f4 __attribute__((ext_vector_type(4)));

// ---------------------------------------------------------------------------
// Fused kernel: GEMM + quantum circuit + post-projection in one launch.
//
// Round-0 geometry (proven fastest): block = 256 threads = 4 waves; each wave
// computes pre-activations for 4 batch rows (16 rows/block, 2048 blocks at
// B=32768 -> ~8 blocks/CU, max wave-level latency hiding for the x stream).
// Changes vs round 0:
//   * all 8 x-loads per wave are explicitly hoisted before any FMA
//     (8 KB in flight per wave, ~64 KB/CU outstanding)
//   * x loads are NON-TEMPORAL: x is a single-use 64 MiB stream; bypassing
//     L2 allocation keeps the per-XCD 4 MiB L2 from thrashing.
// Circuit tail stays on threads 0..15 (issue cost is per-wave-instruction,
// not per-active-lane; round-1 proved the tail is fully hidden).
// ---------------------------------------------------------------------------
__global__ __launch_bounds__(256) void qnet_fused(const float* __restrict__ x,
                                                  const float* __restrict__ w,
                                                  const float* __restrict__ bias,
                                                  const float* __restrict__ u3p,
                                                  const float* __restrict__ post_w,
                                                  const float* __restrict__ post_b,
                                                  float* __restrict__ out,
                                                  int B) {
    __shared__ float lds_pre[64];   // [row_local(16)][q(4)]

    const int wave = (int)(threadIdx.x >> 6);
    const int lane = (int)(threadIdx.x & 63);
    const int block_row0 = (int)blockIdx.x * 16;
    const int row0 = block_row0 + wave * 4;

    // ---- GEMM phase -------------------------------------------------------
    if (row0 < B) {
        // Hoisted x loads: 8 non-temporal dwordx4 in flight per wave.
        f4 xv[4][2];
#pragma unroll
        for (int r = 0; r < 4; ++r) {
            int row = row0 + r;
            if (row >= B) row = B - 1;   // clamp (B%16==0 in practice)
            const f4* xr = (const f4*)(x + (size_t)row * K + lane * 4);
            xv[r][0] = __builtin_nontemporal_load(xr);
            xv[r][1] = __builtin_nontemporal_load(xr + 64);
        }

        f4 wf[NQ][2];
#pragma unroll
        for (int q = 0; q < NQ; ++q) {
#pragma unroll
            for (int h = 0; h < 2; ++h)
                wf[q][h] = *(const f4*)(w + q * K + h * 256 + lane * 4);
        }

        float acc[4][NQ];
#pragma unroll
        for (int r = 0; r < 4; ++r) {
#pragma unroll
            for (int q = 0; q < NQ; ++q) {
                acc[r][q] = xv[r][0][0] * wf[q][0][0] + xv[r][0][1] * wf[q][0][1]
                          + xv[r][0][2] * wf[q][0][2] + xv[r][0][3] * wf[q][0][3]
                          + xv[r][1][0] * wf[q][1][0] + xv[r][1][1] * wf[q][1][1]
                          + xv[r][1][2] * wf[q][1][2] + xv[r][1][3] * wf[q][1][3];
            }
        }

        // Compacting reduction: lane ends with q=(lane&3) total for its row.
        const int l1 = lane & 1;
        const int l2 = lane & 2;
        float v[4];
#pragma unroll
        for (int r = 0; r < 4; ++r) {
            float a01k = l1 ? acc[r][1] : acc[r][0];
            float a01s = l1 ? acc[r][0] : acc[r][1];
            a01k += __shfl_xor(a01s, 1, 64);
            float a23k = l1 ? acc[r][3] : acc[r][2];
            float a23s = l1 ? acc[r][2] : acc[r][3];
            a23k += __shfl_xor(a23s, 1, 64);
            float vk = l2 ? a23k : a01k;
            float vs = l2 ? a01k : a23k;
            vk += __shfl_xor(vs, 2, 64);
#pragma unroll
            for (int off = 4; off <= 32; off <<= 1)
                vk += __shfl_xor(vk, off, 64);
            v[r] = vk;
        }

        if (lane < 16) {
            const int r = lane >> 2;
            const int q = lane & 3;
            float vr = (r == 0) ? v[0] : (r == 1) ? v[1] : (r == 2) ? v[2] : v[3];
            lds_pre[wave * 16 + lane] = vr + bias[q];
        }
    }
    __syncthreads();

    // ---- Circuit phase: threads 0..15, one row each -----------------------
    const int t = (int)threadIdx.x;
    if (t >= 16) return;
    const int b = block_row0 + t;
    if (b >= B) return;

    const float4 pv = *(const float4*)(&lds_pre[t * 4]);
    float pre[NQ] = {pv.x, pv.y, pv.z, pv.w};

    float ry[NQ], rz[NQ];
#pragma unroll
    for (int q = 0; q < NQ; ++q) {
        // tanh(z) = 1 - 2/(exp(2z)+1)
        float z = pre[q] * 0.1f;
        float tnh = 1.0f - 2.0f / (__expf(2.0f * z) + 1.0f);
        float qi = tnh * 1.5707963267948966f;
        ry[q] = atanf(qi);
        rz[q] = atanf(qi * qi);
    }

    // H^4 |0000> = uniform 1/4 (real).
    float sr[DIM], si[DIM];
#pragma unroll
    for (int i = 0; i < DIM; ++i) { sr[i] = 0.25f; si[i] = 0.0f; }

    // RY
#pragma unroll
    for (int q = 0; q < NQ; ++q) {
        float c, s;
        __sincosf(ry[q] * 0.5f, &s, &c);
        const int m = 1 << (3 - q);
#pragma unroll
        for (int i = 0; i < DIM; ++i) {
            if (i & m) continue;
            const int j = i | m;
            float r0 = sr[i], i0 = si[i], r1 = sr[j], i1 = si[j];
            sr[i] = c * r0 - s * r1;  si[i] = c * i0 - s * i1;
            sr[j] = s * r0 + c * r1;  si[j] = s * i0 + c * i1;
        }
    }

    // RZ
#pragma unroll
    for (int q = 0; q < NQ; ++q) {
        float c, s;
        __sincosf(rz[q] * 0.5f, &s, &c);
        const int m = 1 << (3 - q);
#pragma unroll
        for (int i = 0; i < DIM; ++i) {
            const float sg = (i & m) ? s : -s;
            float r = sr[i], im = si[i];
            sr[i] = c * r - sg * im;
            si[i] = c * im + sg * r;
        }
    }

    // CNOT ring step=1 then step=2 (static indices -> pure register renaming)
    const int cn_c[8] = {0, 1, 2, 3, 0, 1, 2, 3};
    const int cn_t[8] = {1, 2, 3, 0, 2, 3, 0, 1};
#pragma unroll
    for (int k = 0; k < 8; ++k) {
        const int cm = 1 << (3 - cn_c[k]);
        const int tm = 1 << (3 - cn_t[k]);
#pragma unroll
        for (int i = 0; i < DIM; ++i) {
            if ((i & cm) && !(i & tm)) {
                const int j = i | tm;
                float tr = sr[i]; sr[i] = sr[j]; sr[j] = tr;
                float ti = si[i]; si[i] = si[j]; si[j] = ti;
            }
        }
    }

    // U3
#pragma unroll
    for (int q = 0; q < NQ; ++q) {
        float th = u3p[q * 3 + 0], ph = u3p[q * 3 + 1], la = u3p[q * 3 + 2];
        float ct, st, cl, sl, cp, sp, cpl, spl;
        __sincosf(th * 0.5f, &st, &ct);
        __sincosf(la, &sl, &cl);
        __sincosf(ph, &sp, &cp);
        __sincosf(ph + la, &spl, &cpl);
        const float g01r = -cl * st, g01i = -sl * st;
        const float g10r = cp * st,  g10i = sp * st;
        const float g11r = cpl * ct, g11i = spl * ct;
        const int m = 1 << (3 - q);
#pragma unroll
        for (int i = 0; i < DIM; ++i) {
            if (i & m) continue;
            const int j = i | m;
            float r0 = sr[i], i0 = si[i], r1 = sr[j], i1 = si[j];
            sr[i] = ct * r0 + g01r * r1 - g01i * i1;
            si[i] = ct * i0 + g01r * i1 + g01i * r1;
            sr[j] = g10r * r0 - g10i * i0 + g11r * r1 - g11i * i1;
            si[j] = g10r * i0 + g10i * r0 + g11r * i1 + g11i * r1;
        }
    }

    // Z expectations + post projection
    float ex[NQ] = {0.f, 0.f, 0.f, 0.f};
#pragma unroll
    for (int i = 0; i < DIM; ++i) {
        const float p2 = sr[i] * sr[i] + si[i] * si[i];
#pragma unroll
        for (int q = 0; q < NQ; ++q)
            ex[q] += (i & (1 << (3 - q))) ? -p2 : p2;
    }

    float o0 = post_b[0], o1 = post_b[1];
#pragma unroll
    for (int q = 0; q < NQ; ++q) {
        o0 += ex[q] * post_w[q];
        o1 += ex[q] * post_w[4 + q];
    }
    *(float2*)(out + (size_t)b * 2) = make_float2(o0, o1);
}

extern "C" void kernel_launch(void* const* d_in, const int* in_sizes, int n_in,
                              void* d_out, int out_size, void* d_ws, size_t ws_size,
                              hipStream_t stream) {
    const float* x      = (const float*)d_in[0];  // [B, 512]
    const float* pre_w  = (const float*)d_in[1];  // [4, 512]
    const float* pre_b  = (const float*)d_in[2];  // [4]
    const float* u3p    = (const float*)d_in[3];  // [4, 3]
    const float* post_w = (const float*)d_in[4];  // [2, 4]
    const float* post_b = (const float*)d_in[5];  // [2]
    float* out = (float*)d_out;                   // [B, 2]

    const int B = in_sizes[0] / K;                // 32768

    const int rows_per_block = 16;
    const int blocks = (B + rows_per_block - 1) / rows_per_block;
    qnet_fused<<<blocks, 256, 0, stream>>>(x, pre_w, pre_b, u3p, post_w, post_b, out, B);
}

// Round 3
// 101.971 us; speedup vs baseline: 1.0473x; 1.0473x over previous
//
#include <hip/hip_runtime.h>
#include <math.h>

#define NQ 4
#define DIM 16
#define K 512

// ---------------------------------------------------------------------------
// Fused kernel: GEMM + quantum circuit + post-projection in one launch.
//
// Round-0 geometry (proven fastest): block = 256 threads = 4 waves; each wave
// computes pre-activations for 4 batch rows (16 rows/block, 2048 blocks at
// B=32768).  Per-wave GEMM: lanes split K=512 as 2x float4; w fragments
// (8 KB) are L1-hot.  Plain cached loads (NT regressed in round 2; hoisting
// was neutral -- compiler already hoists).
//
// Single delta vs round 0: the 4-row reduction is packed into ONE compacting
// tree using lane bits 0-1 for q and bits 2-3 for row: 17 shuffles/wave
// instead of 28, same final layout (lane r*4+q holds pre[row0+r][q]).
// After one __syncthreads, threads 0..15 run the register-resident 4-qubit
// statevector circuit, one row each (tail issue cost is per-wave-instruction;
// round-1 proved it is hidden under other blocks' memory phases).
// ---------------------------------------------------------------------------
__global__ __launch_bounds__(256) void qnet_fused(const float* __restrict__ x,
                                                  const float* __restrict__ w,
                                                  const float* __restrict__ bias,
                                                  const float* __restrict__ u3p,
                                                  const float* __restrict__ post_w,
                                                  const float* __restrict__ post_b,
                                                  float* __restrict__ out,
                                                  int B) {
    __shared__ float lds_pre[64];   // [row_local(16)][q(4)]

    const int wave = (int)(threadIdx.x >> 6);
    const int lane = (int)(threadIdx.x & 63);
    const int block_row0 = (int)blockIdx.x * 16;
    const int row0 = block_row0 + wave * 4;

    // ---- GEMM phase -------------------------------------------------------
    if (row0 < B) {
        float4 wf[NQ][2];
#pragma unroll
        for (int q = 0; q < NQ; ++q) {
#pragma unroll
            for (int h = 0; h < 2; ++h)
                wf[q][h] = *(const float4*)(w + q * K + h * 256 + lane * 4);
        }

        float acc[4][NQ];
#pragma unroll
        for (int r = 0; r < 4; ++r) {
            int row = row0 + r;
            if (row >= B) row = B - 1;   // clamp (B%16==0 in practice)
            const float* xr = x + (size_t)row * K;
            float4 x0 = *(const float4*)(xr + lane * 4);
            float4 x1 = *(const float4*)(xr + 256 + lane * 4);
#pragma unroll
            for (int q = 0; q < NQ; ++q) {
                acc[r][q] = x0.x * wf[q][0].x + x0.y * wf[q][0].y
                          + x0.z * wf[q][0].z + x0.w * wf[q][0].w
                          + x1.x * wf[q][1].x + x1.y * wf[q][1].y
                          + x1.z * wf[q][1].z + x1.w * wf[q][1].w;
            }
        }

        // Packed compacting reduction: q on lane bits 0-1, row on bits 2-3.
        // 17 shuffles total; lane (r*4+q) ends with the full-K pre[row0+r][q].
        const int l1 = lane & 1;
        const int l2 = lane & 2;
        const int l4 = lane & 4;
        const int l8 = lane & 8;

        float vk[4];
#pragma unroll
        for (int r = 0; r < 4; ++r) {
            // stage 1: xor 1 (q bit 0)
            float a01k = l1 ? acc[r][1] : acc[r][0];
            float a01s = l1 ? acc[r][0] : acc[r][1];
            a01k += __shfl_xor(a01s, 1, 64);
            float a23k = l1 ? acc[r][3] : acc[r][2];
            float a23s = l1 ? acc[r][2] : acc[r][3];
            a23k += __shfl_xor(a23s, 1, 64);
            // stage 2: xor 2 (q bit 1)
            float v = l2 ? a23k : a01k;
            float vs = l2 ? a01k : a23k;
            v += __shfl_xor(vs, 2, 64);
            vk[r] = v;   // partial over lane's 4-cluster, q = lane&3
        }

        // stage 3: xor 4 (row bit 0)
        float b01k = l4 ? vk[1] : vk[0];
        float b01s = l4 ? vk[0] : vk[1];
        b01k += __shfl_xor(b01s, 4, 64);
        float b23k = l4 ? vk[3] : vk[2];
        float b23s = l4 ? vk[2] : vk[3];
        b23k += __shfl_xor(b23s, 4, 64);
        // stage 4: xor 8 (row bit 1)
        float ck = l8 ? b23k : b01k;
        float cs = l8 ? b01k : b23k;
        ck += __shfl_xor(cs, 8, 64);
        // stages 5-6: plain butterflies over bits 4-5
        ck += __shfl_xor(ck, 16, 64);
        ck += __shfl_xor(ck, 32, 64);

        if (lane < 16)
            lds_pre[wave * 16 + lane] = ck + bias[lane & 3];
    }
    __syncthreads();

    // ---- Circuit phase: threads 0..15, one row each -----------------------
    const int t = (int)threadIdx.x;
    if (t >= 16) return;
    const int b = block_row0 + t;
    if (b >= B) return;

    float pre[NQ] = {lds_pre[t * 4 + 0], lds_pre[t * 4 + 1],
                     lds_pre[t * 4 + 2], lds_pre[t * 4 + 3]};

    float ry[NQ], rz[NQ];
#pragma unroll
    for (int q = 0; q < NQ; ++q) {
        // tanh(z) = 1 - 2/(exp(2z)+1)
        float z = pre[q] * 0.1f;
        float tnh = 1.0f - 2.0f / (__expf(2.0f * z) + 1.0f);
        float qi = tnh * 1.5707963267948966f;
        ry[q] = atanf(qi);
        rz[q] = atanf(qi * qi);
    }

    // H^4 |0000> = uniform 1/4 (real).
    float sr[DIM], si[DIM];
#pragma unroll
    for (int i = 0; i < DIM; ++i) { sr[i] = 0.25f; si[i] = 0.0f; }

    // RY
#pragma unroll
    for (int q = 0; q < NQ; ++q) {
        float c, s;
        __sincosf(ry[q] * 0.5f, &s, &c);
        const int m = 1 << (3 - q);
#pragma unroll
        for (int i = 0; i < DIM; ++i) {
            if (i & m) continue;
            const int j = i | m;
            float r0 = sr[i], i0 = si[i], r1 = sr[j], i1 = si[j];
            sr[i] = c * r0 - s * r1;  si[i] = c * i0 - s * i1;
            sr[j] = s * r0 + c * r1;  si[j] = s * i0 + c * i1;
        }
    }

    // RZ
#pragma unroll
    for (int q = 0; q < NQ; ++q) {
        float c, s;
        __sincosf(rz[q] * 0.5f, &s, &c);
        const int m = 1 << (3 - q);
#pragma unroll
        for (int i = 0; i < DIM; ++i) {
            const float sg = (i & m) ? s : -s;
            float r = sr[i], im = si[i];
            sr[i] = c * r - sg * im;
            si[i] = c * im + sg * r;
        }
    }

    // CNOT ring step=1 then step=2
    const int cn_c[8] = {0, 1, 2, 3, 0, 1, 2, 3};
    const int cn_t[8] = {1, 2, 3, 0, 2, 3, 0, 1};
#pragma unroll
    for (int k = 0; k < 8; ++k) {
        const int cm = 1 << (3 - cn_c[k]);
        const int tm = 1 << (3 - cn_t[k]);
#pragma unroll
        for (int i = 0; i < DIM; ++i) {
            if ((i & cm) && !(i & tm)) {
                const int j = i | tm;
                float tr = sr[i]; sr[i] = sr[j]; sr[j] = tr;
                float ti = si[i]; si[i] = si[j]; si[j] = ti;
            }
        }
    }

    // U3
#pragma unroll
    for (int q = 0; q < NQ; ++q) {
        float th = u3p[q * 3 + 0], ph = u3p[q * 3 + 1], la = u3p[q * 3 + 2];
        float ct, st, cl, sl, cp, sp, cpl, spl;
        __sincosf(th * 0.5f, &st, &ct);
        __sincosf(la, &sl, &cl);
        __sincosf(ph, &sp, &cp);
        __sincosf(ph + la, &spl, &cpl);
        const float g01r = -cl * st, g01i = -sl * st;
        const float g10r = cp * st,  g10i = sp * st;
        const float g11r = cpl * ct, g11i = spl * ct;
        const int m = 1 << (3 - q);
#pragma unroll
        for (int i = 0; i < DIM; ++i) {
            if (i & m) continue;
            const int j = i | m;
            float r0 = sr[i], i0 = si[i], r1 = sr[j], i1 = si[j];
            sr[i] = ct * r0 + g01r * r1 - g01i * i1;
            si[i] = ct * i0 + g01r * i1 + g01i * r1;
            sr[j] = g10r * r0 - g10i * i0 + g11r * r1 - g11i * i1;
            si[j] = g10r * i0 + g10i * r0 + g11r * i1 + g11i * r1;
        }
    }

    // Z expectations + post projection
    float ex[NQ] = {0.f, 0.f, 0.f, 0.f};
#pragma unroll
    for (int i = 0; i < DIM; ++i) {
        const float p2 = sr[i] * sr[i] + si[i] * si[i];
#pragma unroll
        for (int q = 0; q < NQ; ++q)
            ex[q] += (i & (1 << (3 - q))) ? -p2 : p2;
    }

    float o0 = post_b[0], o1 = post_b[1];
#pragma unroll
    for (int q = 0; q < NQ; ++q) {
        o0 += ex[q] * post_w[q];
        o1 += ex[q] * post_w[4 + q];
    }
    *(float2*)(out + (size_t)b * 2) = make_float2(o0, o1);
}

extern "C" void kernel_launch(void* const* d_in, const int* in_sizes, int n_in,
                              void* d_out, int out_size, void* d_ws, size_t ws_size,
                              hipStream_t stream) {
    const float* x      = (const float*)d_in[0];  // [B, 512]
    const float* pre_w  = (const float*)d_in[1];  // [4, 512]
    const float* pre_b  = (const float*)d_in[2];  // [4]
    const float* u3p    = (const float*)d_in[3];  // [4, 3]
    const float* post_w = (const float*)d_in[4];  // [2, 4]
    const float* post_b = (const float*)d_in[5];  // [2]
    float* out = (float*)d_out;                   // [B, 2]

    const int B = in_sizes[0] / K;                // 32768

    const int rows_per_block = 16;
    const int blocks = (B + rows_per_block - 1) / rows_per_block;
    qnet_fused<<<blocks, 256, 0, stream>>>(x, pre_w, pre_b, u3p, post_w, post_b, out, B);
}